// Round 19
// baseline (54.250 us; speedup 1.0000x reference)
//
#include <hip/hip_runtime.h>
#include <math.h>

// F0Resonance — bit-exact replication of XLA's tiled-scan cumsum (r6..r16).
// phase(j) = fl(A0[j&15] + P1((j>>4)-1)), P1(m)=fl(B1[m&15]+fl(B2[..]+B3[..]))
// contract(off) REQUIRED (r7). Reduction: revolution-space Cody-Waite split
// 1/2pi = I1+I2 (r15) + hw v_sin_f32 (REVOLUTIONS). absmax = 1 bf16 quantum.
//
// r18 lesson: __builtin_amdgcn_readfirstlane takes int — passing a float
// VALUE-converted it (w -> 0.0, output zeros). Fixed with float_as_int /
// int_as_float bitcasts. Structure otherwise = r16 + SGPR-hoisted weights
// + k+1 LDS prefetch (carry + A0 slice) so the 8 independent sin chains
// cover LDS latency (attack r16's 25% lgkm-idle).
#pragma clang fp contract(off)

constexpr int NSAMP = 32768;
constexpr int NROWS = 256;   // B*E = 4*64
constexpr int NOCT  = 16;
constexpr int SEGS  = 16;    // blocks per row (2048 samples each)
constexpr int TPB   = 256;
constexpr int GRID  = NROWS * SEGS;   // 4096

// hard barrier against cross-statement fusion on the scalar chain
__device__ __forceinline__ float keepf(float x) {
  asm volatile("" : "+v"(x));
  return x;
}

__global__ __launch_bounds__(TPB, 8) void f0res_k1(
    const float* __restrict__ f0_in,
    const float* __restrict__ dec_in,
    const float* __restrict__ fs_in,
    float* __restrict__ out,
    float* __restrict__ segmax)
{
  const int bid = blockIdx.x;
  const int row = bid >> 4;
  const int seg = bid & 15;
  const int t   = threadIdx.x;

  __shared__ float s_tab[NOCT][64];   // [0:16)=A0 [16:32)=B1 [32:48)=B2 [48:56)=B3
  __shared__ float s_w[NOCT];
  __shared__ float s_carr[NOCT][128]; // precomputed P1 carries per (k, lm)
  __shared__ float s_red[TPB / 64];

  // ---- fp32 scalar chain (reference roundings; contraction pinned off) ----
  const float f0a = fabsf(f0_in[row]);
  const float dcc = dec_in[row];
  const float fsv = fs_in[row];

  const float MIN_F = (float)(20.0 / 11025.0);
  const float RNG_F = (float)(3000.0 / 11025.0 - 20.0 / 11025.0);
  const float c1s   = keepf(f0a * RNG_F);       // fl32 mul
  const float c2s   = keepf(MIN_F + c1s);       // fl32 add (NOT fma)
  const float f0ang = keepf(c2s * (float)M_PI); // fl32 mul

  const float sg    = 1.0f / (1.0f + expf(-dcc));
  const float dvv   = 1.0f / (1.0f + expf(-sg));   // double sigmoid
  const float dvr   = keepf(dvv * 0.9405f);        // (1-0.01)*0.95
  const float decay = keepf(0.01f + dvr);          // fl32 add (NOT fma)
  const float ldv   = logf(decay + 1e-12f);

  // ---- builder 1: lane k builds octave k's tables + weight ----
  if (t < NOCT) {
    const int k = t;
    float fac = 0.0f;
    for (int j = 0; j <= k; ++j) fac = fac + fsv;   // 16-elem seq cumsum
    const float x = keepf(f0ang * fac);
    float* tab = s_tab[k];
    float a = 0.0f;
#pragma unroll
    for (int i = 0; i < 16; ++i) { a = a + x;  tab[i]      = a; }
    const float T0 = a; a = 0.0f;
#pragma unroll
    for (int i = 0; i < 16; ++i) { a = a + T0; tab[16 + i] = a; }
    const float T1 = a; a = 0.0f;
#pragma unroll
    for (int i = 0; i < 16; ++i) { a = a + T1; tab[32 + i] = a; }
    const float T2 = a; a = 0.0f;
#pragma unroll
    for (int i = 0; i < 8;  ++i) { a = a + T2; tab[48 + i] = a; }
    float lc = 0.0f;
    for (int j = 0; j <= k; ++j) lc = lc + ldv;     // seq cumsum of log_decay
    s_w[k] = expf(lc);
  }
  __syncthreads();

  // ---- builder 2: precompute carries carr[k][lm] = P1(seg*128+lm-1) ----
  // SAME fp32 add order as the per-thread chain (bit-identical).
#pragma unroll
  for (int i = 0; i < (NOCT * 128) / TPB; ++i) {
    const int idx = t + i * TPB;      // 0..2047
    const int k   = idx >> 7;
    const int lm  = idx & 127;
    const int m   = (seg << 7) + lm - 1;
    const float* tab = s_tab[k];
    float c = 0.0f;
    if (m >= 0) {
      c = tab[16 + (m & 15)];
      const int m2 = (m >> 4) - 1;
      if (m2 >= 0) {
        float p2 = tab[32 + (m2 & 15)];
        const int m3 = (m2 >> 4) - 1;
        if (m3 >= 0) p2 = p2 + tab[48 + m3];
        c = c + p2;
      }
    }
    s_carr[k][lm] = c;
  }
  __syncthreads();

  // ---- hoist w[16] into SGPRs (block-uniform; BITCAST, not value-cast) ----
  float wv[NOCT];
#pragma unroll
  for (int k = 0; k < NOCT; ++k)
    wv[k] = __int_as_float(
        __builtin_amdgcn_readfirstlane(__float_as_int(s_w[k])));

  // split 1/(2pi): I1 = fl32(1/2pi), I2 = fl32(1/2pi - I1).
  const double INV2PI_D = 0.15915494309189533577;
  const float I1 = (float)INV2PI_D;
  const float I2 = (float)(INV2PI_D - (double)I1);

  // thread t owns samples j = 8u .. 8u+7, u = seg*256+t (half a scan window)
  const int lm = t >> 1;              // carry index
  const int a0base = (t & 1) * 2;     // float4 index into A0

  float osc[8];
#pragma unroll
  for (int e = 0; e < 8; ++e) osc[e] = 0.0f;

  // ---- k-loop with explicit k+1 prefetch (unroll 1, register rotation) ----
  float carry = s_carr[0][lm];
  float4 tvA = ((const float4*)s_tab[0])[a0base];
  float4 tvB = ((const float4*)s_tab[0])[a0base + 1];

#pragma unroll 1
  for (int k = 0; k < NOCT; ++k) {
    // prefetch next iteration's LDS data before touching this one's
    float carry_n = 0.0f;
    float4 tvA_n = {}, tvB_n = {};
    if (k + 1 < NOCT) {
      carry_n = s_carr[k + 1][lm];
      tvA_n = ((const float4*)s_tab[k + 1])[a0base];
      tvB_n = ((const float4*)s_tab[k + 1])[a0base + 1];
    }

    const float w = wv[k];
    float tv[8];
    *(float4*)&tv[0] = tvA;
    *(float4*)&tv[4] = tvB;

#pragma unroll
    for (int e = 0; e < 8; ++e) {
      const float p  = tv[e] + carry;               // exact ref phase bits
      const float kq = rintf(p * I1);               // nearest rev (mul+rndne)
      float fr = __builtin_fmaf(p, I1, -kq);        // exact prod - kq, 1 rnd
      fr = __builtin_fmaf(p, I2, fr);               // low-bits correction
      float sv;
      asm("v_sin_f32 %0, %1" : "=v"(sv) : "v"(fr)); // sin(fr * 2pi)
      osc[e] = __builtin_fmaf(w, sv, osc[e]);       // output-only fma (r9 ok)
    }

    carry = carry_n; tvA = tvA_n; tvB = tvB_n;
  }

  // ---- block |max| reduction -> plain store (no init, no atomic) ----
  float lmax = 0.0f;
#pragma unroll
  for (int e = 0; e < 8; ++e) lmax = fmaxf(lmax, fabsf(osc[e]));
#pragma unroll
  for (int off = 32; off >= 1; off >>= 1)
    lmax = fmaxf(lmax, __shfl_xor(lmax, off, 64));
  if ((t & 63) == 0) s_red[t >> 6] = lmax;
  __syncthreads();
  if (t == 0) {
    float mx = s_red[0];
#pragma unroll
    for (int i = 1; i < TPB / 64; ++i) mx = fmaxf(mx, s_red[i]);
    segmax[bid] = mx;
  }

  // ---- raw store, block-local PERMUTED layout (lane-contiguous) ----
  // logical f4 l = 2t+q stored at raw slot q*256 + t (1024B/wave runs)
  float4* o4 = (float4*)out + (size_t)bid * 512;
#pragma unroll
  for (int q = 0; q < 2; ++q) {
    float4 v;
    v.x = osc[4 * q + 0];
    v.y = osc[4 * q + 1];
    v.z = osc[4 * q + 2];
    v.w = osc[4 * q + 3];
    o4[q * 256 + t] = v;
  }
}

__global__ __launch_bounds__(TPB, 8) void f0res_k2(
    float* __restrict__ out,
    const float* __restrict__ segmax)
{
  const int bid = blockIdx.x;
  const int t   = threadIdx.x;
  const int row = bid >> 4;

  float mx = 0.0f;
#pragma unroll
  for (int i = 0; i < SEGS; ++i) mx = fmaxf(mx, segmax[row * SEGS + i]);
  const float inv = 1.0f / (mx + 1e-8f);

  float4* base = (float4*)out + (size_t)bid * 512;

  // gather: logical f4 l = q*256+t lives at raw slot (t&1)*256+q*128+(t>>1)
  float4 v[2];
#pragma unroll
  for (int q = 0; q < 2; ++q) {
    const int s = (t & 1) * 256 + q * 128 + (t >> 1);
    v[q] = base[s];
  }
  __syncthreads();   // vmcnt(0) drain: all reads precede writes (in-place ok)
#pragma unroll
  for (int q = 0; q < 2; ++q) {
    float4 x = v[q];
    x.x *= inv; x.y *= inv; x.z *= inv; x.w *= inv;
    base[q * 256 + t] = x;   // linear, lane-contiguous
  }
}

extern "C" void kernel_launch(void* const* d_in, const int* in_sizes, int n_in,
                              void* d_out, int out_size, void* d_ws, size_t ws_size,
                              hipStream_t stream) {
    const float* f0  = (const float*)d_in[0];  // (4,64,1)
    const float* dcc = (const float*)d_in[1];  // decay_coefficients
    // d_in[2] = phase_offsets: computed-but-unused in the reference
    const float* fsp = (const float*)d_in[3];  // freq_spacing
    float* out = (float*)d_out;                // (4,64,32768) fp32
    float* segmax = (float*)d_ws;              // 4096 floats, fully written/call

    f0res_k1<<<GRID, TPB, 0, stream>>>(f0, dcc, fsp, out, segmax);
    f0res_k2<<<GRID, TPB, 0, stream>>>(out, segmax);
}

// Round 20
// 46.996 us; speedup vs baseline: 1.1543x; 1.1543x over previous
//
#include <hip/hip_runtime.h>
#include <math.h>

// F0Resonance — bit-exact replication of XLA's tiled-scan cumsum (r6..r16).
// phase(j) = fl(A0[j&15] + P1((j>>4)-1)), P1(m)=fl(B1[m&15]+fl(B2[..]+B3[..]))
// contract(off) REQUIRED (r7). absmax validated = 1 bf16 quantum.
//
// r20 = r16 skeleton + r17's angle-addition eval WITHOUT the LDS blowup:
//  - r16/r17 controlled pair => v_sin ~13 issue cy (6reg+sin: 36.5 busy/eval;
//    9reg no-sin: 29.4). Removing per-eval sin wins IF occupancy holds.
//  - r17 lost only via 31KB LDS -> 5 blocks/CU + 3x LDS reads. Here sin/cos
//    of the CARRY are computed in registers per k (2 trans + 4 reg, /8
//    evals); only sin/cos(A0) tables (2KB) are added -> LDS 14.9KB, still
//    8 blocks/CU. Eval: Fast2Sum e'=(p-c)-a0 (exact: c>=T0>=a0);
//    sin(p) ~= t1 + e'*t2 (err e'^2/2 <= 1.2e-4 << bf16 q; r17-validated).
#pragma clang fp contract(off)

constexpr int NSAMP = 32768;
constexpr int NROWS = 256;   // B*E = 4*64
constexpr int NOCT  = 16;
constexpr int SEGS  = 16;    // blocks per row (2048 samples each)
constexpr int TPB   = 256;
constexpr int GRID  = NROWS * SEGS;   // 4096

// hard barrier against cross-statement fusion on the scalar chain
__device__ __forceinline__ float keepf(float x) {
  asm volatile("" : "+v"(x));
  return x;
}

__device__ __forceinline__ float hwsin(float fr) {
  float s; asm("v_sin_f32 %0, %1" : "=v"(s) : "v"(fr)); return s;
}
__device__ __forceinline__ float hwcos(float fr) {
  float c; asm("v_cos_f32 %0, %1" : "=v"(c) : "v"(fr)); return c;
}

__global__ __launch_bounds__(TPB, 8) void f0res_k1(
    const float* __restrict__ f0_in,
    const float* __restrict__ dec_in,
    const float* __restrict__ fs_in,
    float* __restrict__ out,
    float* __restrict__ segmax)
{
  const int bid = blockIdx.x;
  const int row = bid >> 4;
  const int seg = bid & 15;
  const int t   = threadIdx.x;

  __shared__ float s_tab[NOCT][64];   // [0:16)=A0 [16:32)=B1 [32:48)=B2 [48:56)=B3
  __shared__ float s_w[NOCT];
  __shared__ float s_carr[NOCT][128]; // precomputed P1 carries per (k, lm)
  __shared__ float s_sa[NOCT][16];    // sin(A0)
  __shared__ float s_ca[NOCT][16];    // cos(A0)
  __shared__ float s_red[TPB / 64];

  // split 1/(2pi): I1 = fl32(1/2pi), I2 = fl32(1/2pi - I1)  (r15-validated)
  const double INV2PI_D = 0.15915494309189533577;
  const float I1 = (float)INV2PI_D;
  const float I2 = (float)(INV2PI_D - (double)I1);

  // ---- fp32 scalar chain (reference roundings; contraction pinned off) ----
  const float f0a = fabsf(f0_in[row]);
  const float dcc = dec_in[row];
  const float fsv = fs_in[row];

  const float MIN_F = (float)(20.0 / 11025.0);
  const float RNG_F = (float)(3000.0 / 11025.0 - 20.0 / 11025.0);
  const float c1s   = keepf(f0a * RNG_F);       // fl32 mul
  const float c2s   = keepf(MIN_F + c1s);       // fl32 add (NOT fma)
  const float f0ang = keepf(c2s * (float)M_PI); // fl32 mul

  const float sg    = 1.0f / (1.0f + expf(-dcc));
  const float dvv   = 1.0f / (1.0f + expf(-sg));   // double sigmoid
  const float dvr   = keepf(dvv * 0.9405f);        // (1-0.01)*0.95
  const float decay = keepf(0.01f + dvr);          // fl32 add (NOT fma)
  const float ldv   = logf(decay + 1e-12f);

  // ---- builder 1: lane k builds octave k's tables + weight ----
  if (t < NOCT) {
    const int k = t;
    float fac = 0.0f;
    for (int j = 0; j <= k; ++j) fac = fac + fsv;   // 16-elem seq cumsum
    const float x = keepf(f0ang * fac);
    float* tab = s_tab[k];
    float a = 0.0f;
#pragma unroll
    for (int i = 0; i < 16; ++i) { a = a + x;  tab[i]      = a; }
    const float T0 = a; a = 0.0f;
#pragma unroll
    for (int i = 0; i < 16; ++i) { a = a + T0; tab[16 + i] = a; }
    const float T1 = a; a = 0.0f;
#pragma unroll
    for (int i = 0; i < 16; ++i) { a = a + T1; tab[32 + i] = a; }
    const float T2 = a; a = 0.0f;
#pragma unroll
    for (int i = 0; i < 8;  ++i) { a = a + T2; tab[48 + i] = a; }
    float lc = 0.0f;
    for (int j = 0; j <= k; ++j) lc = lc + ldv;     // seq cumsum of log_decay
    s_w[k] = expf(lc);
  }
  __syncthreads();

  // ---- builder 2: carries (bit-identical add order) + sin/cos(A0) ----
#pragma unroll
  for (int i = 0; i < (NOCT * 128) / TPB; ++i) {
    const int idx = t + i * TPB;      // 0..2047
    const int k   = idx >> 7;
    const int lm  = idx & 127;
    const int m   = (seg << 7) + lm - 1;
    const float* tab = s_tab[k];
    float c = 0.0f;
    if (m >= 0) {
      c = tab[16 + (m & 15)];
      const int m2 = (m >> 4) - 1;
      if (m2 >= 0) {
        float p2 = tab[32 + (m2 & 15)];
        const int m3 = (m2 >> 4) - 1;
        if (m3 >= 0) p2 = p2 + tab[48 + m3];
        c = c + p2;
      }
    }
    s_carr[k][lm] = c;
  }
  {
    const int k = t >> 4, i = t & 15;     // 256 entries, one per thread
    const float a0 = s_tab[k][i];
    const float kq = rintf(a0 * I1);
    float fr = __builtin_fmaf(a0, I1, -kq);
    fr = __builtin_fmaf(a0, I2, fr);
    s_sa[k][i] = hwsin(fr);
    s_ca[k][i] = hwcos(fr);
  }
  __syncthreads();

  // thread t owns samples j = 8u .. 8u+7, u = seg*256+t (half a scan window)
  const int lm = t >> 1;              // carry index
  const int a0base = (t & 1) * 2;     // float4 index into 16-entry tables

  float osc[8];
#pragma unroll
  for (int e = 0; e < 8; ++e) osc[e] = 0.0f;

#pragma unroll 1   // control register pressure (osc+tv+sa+ca = 32 live)
  for (int k = 0; k < NOCT; ++k) {
    const float carry = s_carr[k][lm];
    const float w     = s_w[k];

    // sin/cos(carry) in REGISTERS: CW-reduce once, 2 trans per k
    const float kqc = rintf(carry * I1);
    float frc = __builtin_fmaf(carry, I1, -kqc);
    frc = __builtin_fmaf(carry, I2, frc);
    const float sC = hwsin(frc);
    const float cC = hwcos(frc);

    float tv[8], sa[8], ca[8];
    *(float4*)&tv[0] = ((const float4*)s_tab[k])[a0base];
    *(float4*)&tv[4] = ((const float4*)s_tab[k])[a0base + 1];
    *(float4*)&sa[0] = ((const float4*)s_sa[k])[a0base];
    *(float4*)&sa[4] = ((const float4*)s_sa[k])[a0base + 1];
    *(float4*)&ca[0] = ((const float4*)s_ca[k])[a0base];
    *(float4*)&ca[4] = ((const float4*)s_ca[k])[a0base + 1];

#pragma unroll
    for (int e = 0; e < 8; ++e) {
      const float p  = tv[e] + carry;     // exact reference phase bits
      const float z  = p - carry;         // Fast2Sum: exact (carry >= a0)
      const float ep = z - tv[e];         // e' = p - (a0+carry), exact
      float t1 = sa[e] * cC;
      t1 = __builtin_fmaf(ca[e], sC, t1);           // sin(a0+carry)
      float t2 = ca[e] * cC;
      t2 = __builtin_fmaf(-sa[e], sC, t2);          // cos(a0+carry)
      const float sv = __builtin_fmaf(ep, t2, t1);  // sin(p) + O(e'^2/2)
      osc[e] = __builtin_fmaf(w, sv, osc[e]);
    }
  }

  // ---- block |max| reduction -> plain store (no init, no atomic) ----
  float lmax = 0.0f;
#pragma unroll
  for (int e = 0; e < 8; ++e) lmax = fmaxf(lmax, fabsf(osc[e]));
#pragma unroll
  for (int off = 32; off >= 1; off >>= 1)
    lmax = fmaxf(lmax, __shfl_xor(lmax, off, 64));
  if ((t & 63) == 0) s_red[t >> 6] = lmax;
  __syncthreads();
  if (t == 0) {
    float mx = s_red[0];
#pragma unroll
    for (int i = 1; i < TPB / 64; ++i) mx = fmaxf(mx, s_red[i]);
    segmax[bid] = mx;
  }

  // ---- raw store, block-local PERMUTED layout (lane-contiguous) ----
  // logical f4 l = 2t+q stored at raw slot q*256 + t (1024B/wave runs)
  float4* o4 = (float4*)out + (size_t)bid * 512;
#pragma unroll
  for (int q = 0; q < 2; ++q) {
    float4 v;
    v.x = osc[4 * q + 0];
    v.y = osc[4 * q + 1];
    v.z = osc[4 * q + 2];
    v.w = osc[4 * q + 3];
    o4[q * 256 + t] = v;
  }
}

__global__ __launch_bounds__(TPB, 8) void f0res_k2(
    float* __restrict__ out,
    const float* __restrict__ segmax)
{
  const int bid = blockIdx.x;
  const int t   = threadIdx.x;
  const int row = bid >> 4;

  float mx = 0.0f;
#pragma unroll
  for (int i = 0; i < SEGS; ++i) mx = fmaxf(mx, segmax[row * SEGS + i]);
  const float inv = 1.0f / (mx + 1e-8f);

  float4* base = (float4*)out + (size_t)bid * 512;

  // gather: logical f4 l = q*256+t lives at raw slot (t&1)*256+q*128+(t>>1)
  float4 v[2];
#pragma unroll
  for (int q = 0; q < 2; ++q) {
    const int s = (t & 1) * 256 + q * 128 + (t >> 1);
    v[q] = base[s];
  }
  __syncthreads();   // vmcnt(0) drain: all reads precede writes (in-place ok)
#pragma unroll
  for (int q = 0; q < 2; ++q) {
    float4 x = v[q];
    x.x *= inv; x.y *= inv; x.z *= inv; x.w *= inv;
    base[q * 256 + t] = x;   // linear, lane-contiguous
  }
}

extern "C" void kernel_launch(void* const* d_in, const int* in_sizes, int n_in,
                              void* d_out, int out_size, void* d_ws, size_t ws_size,
                              hipStream_t stream) {
    const float* f0  = (const float*)d_in[0];  // (4,64,1)
    const float* dcc = (const float*)d_in[1];  // decay_coefficients
    // d_in[2] = phase_offsets: computed-but-unused in the reference
    const float* fsp = (const float*)d_in[3];  // freq_spacing
    float* out = (float*)d_out;                // (4,64,32768) fp32
    float* segmax = (float*)d_ws;              // 4096 floats, fully written/call

    f0res_k1<<<GRID, TPB, 0, stream>>>(f0, dcc, fsp, out, segmax);
    f0res_k2<<<GRID, TPB, 0, stream>>>(out, segmax);
}

// Round 21
// 45.957 us; speedup vs baseline: 1.1804x; 1.0226x over previous
//
#include <hip/hip_runtime.h>
#include <math.h>

// F0Resonance — bit-exact replication of XLA's tiled-scan cumsum (r6..r16).
// jnp.cumsum lowers via ReduceWindowRewriter, base B=16: [32768]->[2048,16],
// sequential fp32 inner scans, recursive carry scan (2048->128->8), one fp32
// combine-add per level. phase(j) = fl(A0[j&15] + P1((j>>4)-1)),
// P1(m)=fl(B1[m&15]+fl(B2[m2&15]+B3[m3])). contract(off) REQUIRED (r7: hipcc
// fuses mul+add -> f0ang off 1 ulp -> 0.03 rad at n=32768).
// Reduction: revolution-space Cody-Waite split 1/2pi = I1+I2 (r15, ~6e-7
// rad arg err) + hw v_sin_f32 (REVOLUTIONS). Validated absmax = 1 bf16 q.
//
// FINAL (r21 = r16 verbatim, the measured best at 45.6us total):
// the r14-r20 exploration mapped the plateau — fewer instructions => more
// stalls (r17/r20 angle-addition), manual prefetch => more instructions
// (r18/r19), carry hoist => neutral (r16). Per-eval floor = 6 regular VALU
// + v_sin(~13cy) ~= 25cy; overhead+stalls put K1 at ~41.5us, K2 ~4us.
#pragma clang fp contract(off)

constexpr int NSAMP = 32768;
constexpr int NROWS = 256;   // B*E = 4*64
constexpr int NOCT  = 16;
constexpr int SEGS  = 16;    // blocks per row (2048 samples each)
constexpr int TPB   = 256;
constexpr int GRID  = NROWS * SEGS;   // 4096

// hard barrier against cross-statement fusion on the scalar chain
__device__ __forceinline__ float keepf(float x) {
  asm volatile("" : "+v"(x));
  return x;
}

__global__ __launch_bounds__(TPB, 8) void f0res_k1(
    const float* __restrict__ f0_in,
    const float* __restrict__ dec_in,
    const float* __restrict__ fs_in,
    float* __restrict__ out,
    float* __restrict__ segmax)
{
  const int bid = blockIdx.x;
  const int row = bid >> 4;
  const int seg = bid & 15;
  const int t   = threadIdx.x;

  __shared__ float s_tab[NOCT][64];   // [0:16)=A0 [16:32)=B1 [32:48)=B2 [48:56)=B3
  __shared__ float s_w[NOCT];
  __shared__ float s_carr[NOCT][128]; // precomputed P1 carries per (k, lm)
  __shared__ float s_red[TPB / 64];

  // ---- fp32 scalar chain (reference roundings; contraction pinned off) ----
  const float f0a = fabsf(f0_in[row]);
  const float dcc = dec_in[row];
  const float fsv = fs_in[row];

  const float MIN_F = (float)(20.0 / 11025.0);
  const float RNG_F = (float)(3000.0 / 11025.0 - 20.0 / 11025.0);
  const float c1s   = keepf(f0a * RNG_F);       // fl32 mul
  const float c2s   = keepf(MIN_F + c1s);       // fl32 add (NOT fma)
  const float f0ang = keepf(c2s * (float)M_PI); // fl32 mul

  const float sg    = 1.0f / (1.0f + expf(-dcc));
  const float dvv   = 1.0f / (1.0f + expf(-sg));   // double sigmoid
  const float dvr   = keepf(dvv * 0.9405f);        // (1-0.01)*0.95
  const float decay = keepf(0.01f + dvr);          // fl32 add (NOT fma)
  const float ldv   = logf(decay + 1e-12f);

  // ---- builder 1: lane k builds octave k's tables + weight ----
  if (t < NOCT) {
    const int k = t;
    float fac = 0.0f;
    for (int j = 0; j <= k; ++j) fac = fac + fsv;   // 16-elem seq cumsum
    const float x = keepf(f0ang * fac);
    float* tab = s_tab[k];
    float a = 0.0f;
#pragma unroll
    for (int i = 0; i < 16; ++i) { a = a + x;  tab[i]      = a; }
    const float T0 = a; a = 0.0f;
#pragma unroll
    for (int i = 0; i < 16; ++i) { a = a + T0; tab[16 + i] = a; }
    const float T1 = a; a = 0.0f;
#pragma unroll
    for (int i = 0; i < 16; ++i) { a = a + T1; tab[32 + i] = a; }
    const float T2 = a; a = 0.0f;
#pragma unroll
    for (int i = 0; i < 8;  ++i) { a = a + T2; tab[48 + i] = a; }
    float lc = 0.0f;
    for (int j = 0; j <= k; ++j) lc = lc + ldv;     // seq cumsum of log_decay
    s_w[k] = expf(lc);
  }
  __syncthreads();

  // ---- builder 2: precompute carries carr[k][lm] = P1(seg*128+lm-1) ----
  // SAME fp32 add order as the reference chain (bit-identical).
#pragma unroll
  for (int i = 0; i < (NOCT * 128) / TPB; ++i) {
    const int idx = t + i * TPB;      // 0..2047
    const int k   = idx >> 7;
    const int lm  = idx & 127;
    const int m   = (seg << 7) + lm - 1;
    const float* tab = s_tab[k];
    float c = 0.0f;
    if (m >= 0) {
      c = tab[16 + (m & 15)];
      const int m2 = (m >> 4) - 1;
      if (m2 >= 0) {
        float p2 = tab[32 + (m2 & 15)];
        const int m3 = (m2 >> 4) - 1;
        if (m3 >= 0) p2 = p2 + tab[48 + m3];
        c = c + p2;
      }
    }
    s_carr[k][lm] = c;
  }
  __syncthreads();

  // split 1/(2pi): I1 = fl32(1/2pi), I2 = fl32(1/2pi - I1).
  const double INV2PI_D = 0.15915494309189533577;
  const float I1 = (float)INV2PI_D;
  const float I2 = (float)(INV2PI_D - (double)I1);

  // thread t owns samples j = 8u .. 8u+7, u = seg*256+t (half a scan window)
  const int lm = t >> 1;              // carry index
  const int a0base = (t & 1) * 2;     // float4 index into A0

  float osc[8];
#pragma unroll
  for (int e = 0; e < 8; ++e) osc[e] = 0.0f;

#pragma unroll 2   // amortize per-k overhead, keep regs < 64
  for (int k = 0; k < NOCT; ++k) {
    const float carry = s_carr[k][lm];         // 1 b32, broadcast-friendly
    const float w = s_w[k];

    // A0 slice into registers (2 x ds_read_b128, 2 addrs -> broadcast)
    float tv[8];
    *(float4*)&tv[0] = ((const float4*)s_tab[k])[a0base];
    *(float4*)&tv[4] = ((const float4*)s_tab[k])[a0base + 1];

#pragma unroll
    for (int e = 0; e < 8; ++e) {
      const float p  = tv[e] + carry;               // exact ref phase bits
      const float kq = rintf(p * I1);               // nearest rev (mul+rndne)
      float fr = __builtin_fmaf(p, I1, -kq);        // exact prod - kq, 1 rnd
      fr = __builtin_fmaf(p, I2, fr);               // low-bits correction
      float sv;
      asm("v_sin_f32 %0, %1" : "=v"(sv) : "v"(fr)); // sin(fr * 2pi)
      // fma on OUTPUT accumulation only (phase untouched): validated r9.
      osc[e] = __builtin_fmaf(w, sv, osc[e]);
    }
  }

  // ---- block |max| reduction -> plain store (no init, no atomic) ----
  float lmax = 0.0f;
#pragma unroll
  for (int e = 0; e < 8; ++e) lmax = fmaxf(lmax, fabsf(osc[e]));
#pragma unroll
  for (int off = 32; off >= 1; off >>= 1)
    lmax = fmaxf(lmax, __shfl_xor(lmax, off, 64));
  if ((t & 63) == 0) s_red[t >> 6] = lmax;
  __syncthreads();
  if (t == 0) {
    float mx = s_red[0];
#pragma unroll
    for (int i = 1; i < TPB / 64; ++i) mx = fmaxf(mx, s_red[i]);
    segmax[bid] = mx;
  }

  // ---- raw store, block-local PERMUTED layout (lane-contiguous) ----
  // logical f4 l = 2t+q stored at raw slot q*256 + t (1024B/wave runs)
  float4* o4 = (float4*)out + (size_t)bid * 512;
#pragma unroll
  for (int q = 0; q < 2; ++q) {
    float4 v;
    v.x = osc[4 * q + 0];
    v.y = osc[4 * q + 1];
    v.z = osc[4 * q + 2];
    v.w = osc[4 * q + 3];
    o4[q * 256 + t] = v;
  }
}

__global__ __launch_bounds__(TPB, 8) void f0res_k2(
    float* __restrict__ out,
    const float* __restrict__ segmax)
{
  const int bid = blockIdx.x;
  const int t   = threadIdx.x;
  const int row = bid >> 4;

  float mx = 0.0f;
#pragma unroll
  for (int i = 0; i < SEGS; ++i) mx = fmaxf(mx, segmax[row * SEGS + i]);
  const float inv = 1.0f / (mx + 1e-8f);

  float4* base = (float4*)out + (size_t)bid * 512;

  // gather: logical f4 l = q*256+t lives at raw slot (t&1)*256+q*128+(t>>1)
  float4 v[2];
#pragma unroll
  for (int q = 0; q < 2; ++q) {
    const int s = (t & 1) * 256 + q * 128 + (t >> 1);
    v[q] = base[s];
  }
  __syncthreads();   // vmcnt(0) drain: all reads precede writes (in-place ok)
#pragma unroll
  for (int q = 0; q < 2; ++q) {
    float4 x = v[q];
    x.x *= inv; x.y *= inv; x.z *= inv; x.w *= inv;
    base[q * 256 + t] = x;   // linear, lane-contiguous
  }
}

extern "C" void kernel_launch(void* const* d_in, const int* in_sizes, int n_in,
                              void* d_out, int out_size, void* d_ws, size_t ws_size,
                              hipStream_t stream) {
    const float* f0  = (const float*)d_in[0];  // (4,64,1)
    const float* dcc = (const float*)d_in[1];  // decay_coefficients
    // d_in[2] = phase_offsets: computed-but-unused in the reference
    const float* fsp = (const float*)d_in[3];  // freq_spacing
    float* out = (float*)d_out;                // (4,64,32768) fp32
    float* segmax = (float*)d_ws;              // 4096 floats, fully written/call

    f0res_k1<<<GRID, TPB, 0, stream>>>(f0, dcc, fsp, out, segmax);
    f0res_k2<<<GRID, TPB, 0, stream>>>(out, segmax);
}